// Round 1
// 304.311 us; speedup vs baseline: 1.0050x; 1.0050x over previous
//
#include <hip/hip_runtime.h>
#include <hip/hip_bf16.h>

typedef __hip_bfloat16 bf16;
typedef short bf16x8 __attribute__((ext_vector_type(8)));
typedef float f32x4 __attribute__((ext_vector_type(4)));

#define MFMA16(a,b,c) __builtin_amdgcn_mfma_f32_16x16x32_bf16(a,b,c,0,0,0)

__device__ __forceinline__ unsigned short f2us(float x){
    union{__hip_bfloat16 h; unsigned short u;} c; c.h = __float2bfloat16(x); return c.u;
}
__device__ __forceinline__ float us2f(unsigned short u){
    union{unsigned short u; __hip_bfloat16 h;} c; c.u = u; return __bfloat162float(c.h);
}
__device__ __forceinline__ uint4 pack8(float4 a, float4 b){
    union{unsigned short us[8]; uint4 v;} p;
    p.us[0]=f2us(a.x); p.us[1]=f2us(a.y); p.us[2]=f2us(a.z); p.us[3]=f2us(a.w);
    p.us[4]=f2us(b.x); p.us[5]=f2us(b.y); p.us[6]=f2us(b.z); p.us[7]=f2us(b.w);
    return p.v;
}

// ---------------------------------------------------------------------------
// prep: LDS-tiled transposes (unchanged).
// ---------------------------------------------------------------------------
__global__ __launch_bounds__(256) void prep_kernel(
    const float* __restrict__ Wq, const float* __restrict__ Wk,
    const float* __restrict__ Wv, const float* __restrict__ bq,
    const float* __restrict__ bk, const float* __restrict__ bv,
    const float* __restrict__ Wo,
    bf16* __restrict__ WqT, bf16* __restrict__ WkT, bf16* __restrict__ WvT,
    float* __restrict__ bqp, float* __restrict__ bkp, float* __restrict__ bvp,
    bf16* __restrict__ WoT)
{
    __shared__ float T[64][68];
    const int tid = threadIdx.x, bx = blockIdx.x;
    if (bx < 384) {
        const int mat = bx / 128, rem = bx % 128;
        const int c0 = (rem >> 5) * 64, n0 = (rem & 31) * 64;
        const float* W = (mat == 0) ? Wq : (mat == 1) ? Wk : Wv;
        bf16* WT = (mat == 0) ? WqT : (mat == 1) ? WkT : WvT;
        #pragma unroll
        for (int it = 0; it < 4; ++it) {
            int pp = tid + (it << 8);
            int cl = pp >> 4, n4 = (pp & 15) * 4;
            float4 f = *(const float4*)(W + (size_t)(c0 + cl) * 2048 + n0 + n4);
            T[cl][n4] = f.x; T[cl][n4+1] = f.y; T[cl][n4+2] = f.z; T[cl][n4+3] = f.w;
        }
        __syncthreads();
        const int h = n0 >> 8, d0 = n0 & 255;
        #pragma unroll
        for (int it = 0; it < 2; ++it) {
            int pp = tid + (it << 8);
            int j = pp >> 3, g = pp & 7;
            union{unsigned short us[8]; uint4 v;} pk;
            #pragma unroll
            for (int u = 0; u < 8; ++u) pk.us[u] = f2us(T[g*8+u][j]);
            *(uint4*)(WT + (size_t)((d0 + j) * 8 + h) * 256 + c0 + g * 8) = pk.v;
        }
    } else if (bx < 387) {
        const int mat = bx - 384;
        const float* src = (mat == 0) ? bq : (mat == 1) ? bk : bv;
        float* dst = (mat == 0) ? bqp : (mat == 1) ? bkp : bvp;
        for (int n = tid; n < 2048; n += 256)
            dst[(n & 255) * 8 + (n >> 8)] = src[n];
    } else {
        const int idx = bx - 387;
        const int k0 = (idx >> 2) * 64, c0 = (idx & 3) * 64;
        #pragma unroll
        for (int it = 0; it < 4; ++it) {
            int pp = tid + (it << 8);
            int kl = pp >> 4, c4 = (pp & 15) * 4;
            float4 f = *(const float4*)(Wo + (size_t)(k0 + kl) * 256 + c0 + c4);
            T[kl][c4] = f.x; T[kl][c4+1] = f.y; T[kl][c4+2] = f.z; T[kl][c4+3] = f.w;
        }
        __syncthreads();
        #pragma unroll
        for (int it = 0; it < 2; ++it) {
            int pp = tid + (it << 8);
            int j = pp >> 3, g = pp & 7;
            union{unsigned short us[8]; uint4 v;} pk;
            #pragma unroll
            for (int u = 0; u < 8; ++u) pk.us[u] = f2us(T[g*8+u][j]);
            *(uint4*)(WoT + (size_t)(c0 + j) * 2048 + k0 + g * 8) = pk.v;
        }
    }
}

// ---------------------------------------------------------------------------
// qk v2: 64 tokens/block, 512 threads, grid 256. Each wave now owns a
// 32-column slice (nt=0,1) of the 256-col Cp chunk, so each Xq/Xk A-frag
// ds_read_b128 feeds 4 MFMAs instead of 2 -> LDS read traffic halves
// (8192 -> 4096 ds_read_b128 per block). QT/KT round-trip, score MFMA,
// and softmax phases unchanged. __launch_bounds__(512,2) grants the
// 256-VGPR budget matching the LDS-capped 2 waves/SIMD occupancy.
// ---------------------------------------------------------------------------
__global__ __launch_bounds__(512, 2) void qk_kernel(
    const float* __restrict__ Qin, const float* __restrict__ Kin,
    const int* __restrict__ mask,
    const bf16* __restrict__ WqT, const bf16* __restrict__ WkT,
    const float* __restrict__ bqp, const float* __restrict__ bkp,
    float* __restrict__ w)
{
    __shared__ __align__(16) char smem[147456];
    char* const Xq = smem;             // [64][256] bf16 swizzled (32 KB)
    char* const Xk = smem + 32768;     // 32 KB
    char* const QT = smem + 65536;     // [256 p2][pitch 160B] (40 KB)
    char* const KT = smem + 106496;    // 40 KB
    float* const RED = (float*)smem;   // [64][68] fp32 alias over Xq

    const int tid  = threadIdx.x;
    const int wid  = tid >> 6, lane = tid & 63;
    const int quad = lane >> 4, l15 = lane & 15;
    const int tok0 = blockIdx.x * 64;

    // stage Xq, Xk once (fp32 -> bf16, XOR-swizzled 16B groups)
    #pragma unroll
    for (int it = 0; it < 4; ++it) {
        int pp = tid + (it << 9);
        int row = pp >> 5, g = pp & 31;
        const float* s = Qin + (size_t)(tok0 + row) * 256 + g * 8;
        *(uint4*)(Xq + row * 512 + ((g ^ (row & 7)) << 4)) =
            pack8(*(const float4*)s, *(const float4*)(s + 4));
        s = Kin + (size_t)(tok0 + row) * 256 + g * 8;
        *(uint4*)(Xk + row * 512 + ((g ^ (row & 7)) << 4)) =
            pack8(*(const float4*)s, *(const float4*)(s + 4));
    }
    __syncthreads();

    f32x4 sacc[4];
    #pragma unroll
    for (int p = 0; p < 4; ++p)
        #pragma unroll
        for (int i = 0; i < 4; ++i) sacc[p][i] = 0.f;

    for (int Cp = 0; Cp < 8; ++Cp) {
        // --- projection: wave computes 64 tokens x 32 cols for Q and K ---
        f32x4 accq[4][2], acck[4][2];
        #pragma unroll
        for (int mt = 0; mt < 4; ++mt)
            #pragma unroll
            for (int nt = 0; nt < 2; ++nt)
                #pragma unroll
                for (int i = 0; i < 4; ++i) { accq[mt][nt][i] = 0.f; acck[mt][nt][i] = 0.f; }
        #pragma unroll
        for (int Ks = 0; Ks < 8; ++Ks) {
            bf16x8 bq[2], bk[2];
            #pragma unroll
            for (int nt = 0; nt < 2; ++nt) {
                const size_t boff =
                    (size_t)(Cp * 256 + wid * 32 + nt * 16 + l15) * 256 + Ks * 32 + quad * 8;
                bq[nt] = *(const bf16x8*)(WqT + boff);
                bk[nt] = *(const bf16x8*)(WkT + boff);
            }
            #pragma unroll
            for (int mt = 0; mt < 4; ++mt) {
                int row = mt * 16 + l15;
                int G = (Ks * 4 + quad) ^ (row & 7);
                bf16x8 aq = *(const bf16x8*)(Xq + row * 512 + (G << 4));
                bf16x8 ak = *(const bf16x8*)(Xk + row * 512 + (G << 4));
                #pragma unroll
                for (int nt = 0; nt < 2; ++nt) {
                    accq[mt][nt] = MFMA16(aq, bq[nt], accq[mt][nt]);
                    acck[mt][nt] = MFMA16(ak, bk[nt], acck[mt][nt]);
                }
            }
        }
        #pragma unroll
        for (int nt = 0; nt < 2; ++nt) {
            const int p2 = wid * 32 + nt * 16 + l15;
            const int rowoff = p2 * 160 + ((p2 >> 6) & 3) * 8;
            const float biq = bqp[Cp * 256 + p2];
            const float bik = bkp[Cp * 256 + p2];
            #pragma unroll
            for (int mt = 0; mt < 4; ++mt) {
                int t0 = mt * 16 + quad * 4;
                union{unsigned short us[4]; uint2 v;} pq, pk;
                #pragma unroll
                for (int i = 0; i < 4; ++i) {
                    pq.us[i] = f2us(accq[mt][nt][i] + biq);
                    pk.us[i] = f2us(acck[mt][nt][i] + bik);
                }
                *(uint2*)(QT + rowoff + t0 * 2) = pq.v;
                *(uint2*)(KT + rowoff + t0 * 2) = pk.v;
            }
        }
        __syncthreads();
        // block-diagonal score MFMA: 4 token-pairs per wave
        #pragma unroll
        for (int pp2 = 0; pp2 < 4; ++pp2) {
            int tq = 2 * (wid * 4 + pp2) + (l15 >> 3);
            union{unsigned short us[8]; bf16x8 v;} Aq, Bk;
            #pragma unroll
            for (int j = 0; j < 8; ++j) {
                int p2 = (quad * 8 + j) * 8 + (l15 & 7);
                int off = p2 * 160 + ((p2 >> 6) & 3) * 8 + tq * 2;
                Aq.us[j] = *(const unsigned short*)(QT + off);
                Bk.us[j] = *(const unsigned short*)(KT + off);
            }
            sacc[pp2] = MFMA16(Aq.v, Bk.v, sacc[pp2]);
        }
        __syncthreads();
    }

    // diagonal extraction -> RED[t][h*8+g]
    if ((quad >> 1) == (l15 >> 3)) {
        #pragma unroll
        for (int pp2 = 0; pp2 < 4; ++pp2) {
            int tl = (wid * 4 + pp2) * 2 + (l15 >> 3);
            #pragma unroll
            for (int i = 0; i < 4; ++i)
                RED[tl * 68 + ((quad & 1) * 4 + i) * 8 + (l15 & 7)] = sacc[pp2][i];
        }
    }
    __syncthreads();
    // softmax: thread (tl, h)
    {
        const int tl = tid >> 3, hh = tid & 7;
        const int mk = mask[tok0 + tl];
        const float* r = RED + tl * 68 + hh * 8;
        float m = r[0];
        #pragma unroll
        for (int g = 1; g < 8; ++g) m = fmaxf(m, r[g]);
        float e[8], sum = 0.f;
        #pragma unroll
        for (int g = 0; g < 8; ++g) { e[g] = __expf((r[g] - m) * 0.0625f); sum += e[g]; }
        float inv = 1.f / sum;
        float o[8];
        #pragma unroll
        for (int g = 0; g < 8; ++g) o[g] = mk ? e[g] * inv : 0.125f;
        float* wp = w + (size_t)(tok0 + tl) * 64 + hh * 8;
        *(float4*)wp = make_float4(o[0], o[1], o[2], o[3]);
        *(float4*)(wp + 4) = make_float4(o[4], o[5], o[6], o[7]);
    }
}

// ---------------------------------------------------------------------------
// v_attn: unchanged.
// ---------------------------------------------------------------------------
__global__ __launch_bounds__(512) void v_attn_kernel(
    const float* __restrict__ Vin,
    const bf16* __restrict__ WvT, const float* __restrict__ bvp,
    const float* __restrict__ w, bf16* __restrict__ A)
{
    __shared__ __align__(16) char smem[66560];
    char* const Xv = smem;             // [64][256] bf16 swizzled (32 KB)
    char* const VT = smem + 32768;     // [128 p][pitch 136B] (17408 B)
    char* const xS = smem + 50176;     // [64 t][16 units x 16B swizzled] (16 KB)

    const int tid  = threadIdx.x;
    const int wid  = tid >> 6, lane = tid & 63;
    const int quad = lane >> 4, l15 = lane & 15;
    const int tok0 = blockIdx.x * 64;
    const int t6   = tid & 63, dg = tid >> 6;

    #pragma unroll
    for (int it = 0; it < 4; ++it) {
        int pp = tid + (it << 9);
        int row = pp >> 5, g = pp & 31;
        const float* s = Vin + (size_t)(tok0 + row) * 256 + g * 8;
        *(uint4*)(Xv + row * 512 + ((g ^ (row & 7)) << 4)) =
            pack8(*(const float4*)s, *(const float4*)(s + 4));
    }
    float wv[64];
    {
        const float* wp = w + (size_t)(tok0 + t6) * 64;
        #pragma unroll
        for (int i = 0; i < 16; ++i) {
            float4 f = ((const float4*)wp)[i];
            wv[i*4] = f.x; wv[i*4+1] = f.y; wv[i*4+2] = f.z; wv[i*4+3] = f.w;
        }
    }
    __syncthreads();

    const int pll = wid * 16 + l15;

    for (int C = 0; C < 16; ++C) {
        f32x4 acc[4];
        #pragma unroll
        for (int mt = 0; mt < 4; ++mt)
            #pragma unroll
            for (int i = 0; i < 4; ++i) acc[mt][i] = 0.f;
        #pragma unroll
        for (int Ks = 0; Ks < 8; ++Ks) {
            bf16x8 b = *(const bf16x8*)(WvT + (size_t)(C * 128 + pll) * 256 + Ks * 32 + quad * 8);
            #pragma unroll
            for (int mt = 0; mt < 4; ++mt) {
                int row = mt * 16 + l15;
                int G = (Ks * 4 + quad) ^ (row & 7);
                bf16x8 a = *(const bf16x8*)(Xv + row * 512 + (G << 4));
                acc[mt] = MFMA16(a, b, acc[mt]);
            }
        }
        const float biv = bvp[C * 128 + pll];
        #pragma unroll
        for (int mt = 0; mt < 4; ++mt) {
            int t0 = mt * 16 + quad * 4;
            union{unsigned short us[4]; uint2 v;} pk;
            #pragma unroll
            for (int i = 0; i < 4; ++i) pk.us[i] = f2us(acc[mt][i] + biv);
            *(uint2*)(VT + pll * 136 + t0 * 2) = pk.v;
        }
        __syncthreads();
        // weighted sum: thread (t6, dg) covers d = dg*2 + {0,1}
        #pragma unroll
        for (int dd = 0; dd < 2; ++dd) {
            int d = dg * 2 + dd;
            float vv[8];
            #pragma unroll
            for (int g = 0; g < 8; ++g)
                vv[g] = us2f(*(const unsigned short*)(VT + (d * 8 + g) * 136 + t6 * 2));
            #pragma unroll
            for (int h = 0; h < 8; ++h) {
                float x = 0.f;
                #pragma unroll
                for (int g = 0; g < 8; ++g) x = fmaf(wv[h * 8 + g], vv[g], x);
                int u = (h * 2 + (d >> 3)) ^ (t6 & 15);
                *(unsigned short*)(xS + t6 * 256 + u * 16 + (d & 7) * 2) = f2us(x);
            }
        }
        __syncthreads();
        // scrambled store: thread (t, h) writes 32 B
        {
            int t = tid >> 3, hh = tid & 7;
            int tok = tok0 + t;
            int b = tok >> 11, sr = tok & 2047, sg = sr >> 3, j = sr & 7;
            size_t r = ((size_t)b << 11) + hh * 256 + sg;
            bf16* dst = A + r * 2048 + j * 256 + C * 16;
            int u0 = (hh * 2) ^ (t & 15), u1 = (hh * 2 + 1) ^ (t & 15);
            *(uint4*)dst       = *(const uint4*)(xS + t * 256 + u0 * 16);
            *(uint4*)(dst + 8) = *(const uint4*)(xS + t * 256 + u1 * 16);
        }
    }
}

// ---------------------------------------------------------------------------
// outproj: unchanged.
// ---------------------------------------------------------------------------
__global__ __launch_bounds__(256) void outproj_kernel(
    const bf16* __restrict__ A, const bf16* __restrict__ WoT,
    const float* __restrict__ Wo, const float* __restrict__ bo,
    float* __restrict__ Out)
{
    __shared__ __align__(16) char smem[24576];
    char* const AsS = smem;
    char* const Ws  = smem + 8192;

    const int tid = threadIdx.x;
    const int wave = tid >> 6, lane = tid & 63, quad = lane >> 4, l15 = lane & 15;
    const int R = blockIdx.x >> 1, C = blockIdx.x & 1;
    const int row0 = R * 64, col0 = C * 128;

    f32x4 acc[4][2];
    #pragma unroll
    for (int mt = 0; mt < 4; ++mt)
        #pragma unroll
        for (int nt = 0; nt < 2; ++nt)
            #pragma unroll
            for (int i = 0; i < 4; ++i) acc[mt][nt][i] = 0.f;

    for (int kc = 0; kc < 32; ++kc) {
        __syncthreads();
        #pragma unroll
        for (int it = 0; it < 2; ++it) {
            int pp = tid + (it << 8);
            int rho = pp >> 3, g = pp & 7;
            *(uint4*)(AsS + rho * 128 + ((g ^ (rho & 7)) << 4)) =
                *(const uint4*)(A + (size_t)(row0 + rho) * 2048 + kc * 64 + g * 8);
        }
        if (WoT != nullptr) {
            #pragma unroll
            for (int it = 0; it < 4; ++it) {
                int pp = tid + (it << 8);
                int cl = pp >> 3, g = pp & 7;
                *(uint4*)(Ws + cl * 128 + ((g ^ (cl & 7)) << 4)) =
                    *(const uint4*)(WoT + (size_t)(col0 + cl) * 2048 + kc * 64 + g * 8);
            }
        } else {
            #pragma unroll
            for (int it = 0; it < 8; ++it) {
                int pp = tid + (it << 8);
                int kl = pp >> 5, c4 = (pp & 31) * 4;
                float4 f = *(const float4*)(Wo + (size_t)(kc * 64 + kl) * 256 + col0 + c4);
                float fv[4] = {f.x, f.y, f.z, f.w};
                #pragma unroll
                for (int u = 0; u < 4; ++u) {
                    int cl = c4 + u;
                    *(unsigned short*)(Ws + cl * 128 + (((kl >> 3) ^ (cl & 7)) << 4) + (kl & 7) * 2)
                        = f2us(fv[u]);
                }
            }
        }
        __syncthreads();
        #pragma unroll
        for (int ks = 0; ks < 2; ++ks) {
            bf16x8 a[4], b[2];
            #pragma unroll
            for (int mt = 0; mt < 4; ++mt) {
                int row = mt * 16 + l15;
                int G = (ks * 4 + quad) ^ (row & 7);
                a[mt] = *(const bf16x8*)(AsS + row * 128 + (G << 4));
            }
            #pragma unroll
            for (int nt = 0; nt < 2; ++nt) {
                int cl = wave * 32 + nt * 16 + l15;
                int G = (ks * 4 + quad) ^ (cl & 7);
                b[nt] = *(const bf16x8*)(Ws + cl * 128 + (G << 4));
            }
            #pragma unroll
            for (int mt = 0; mt < 4; ++mt)
                #pragma unroll
                for (int nt = 0; nt < 2; ++nt)
                    acc[mt][nt] = MFMA16(a[mt], b[nt], acc[mt][nt]);
        }
    }
    #pragma unroll
    for (int nt = 0; nt < 2; ++nt) {
        int col = col0 + wave * 32 + nt * 16 + l15;
        float bias = bo[col];
        #pragma unroll
        for (int mt = 0; mt < 4; ++mt) {
            int r0 = row0 + mt * 16 + quad * 4;
            #pragma unroll
            for (int i = 0; i < 4; ++i)
                Out[(size_t)(r0 + i) * 256 + col] = acc[mt][nt][i] + bias;
        }
    }
}

// ---------------------------------------------------------------------------
extern "C" void kernel_launch(void* const* d_in, const int* in_sizes, int n_in,
                              void* d_out, int out_size, void* d_ws, size_t ws_size,
                              hipStream_t stream) {
    const float* query = (const float*)d_in[0];
    const float* key   = (const float*)d_in[1];
    const float* value = (const float*)d_in[2];
    const int*   mask  = (const int*)  d_in[3];
    const float* Wq = (const float*)d_in[4];  const float* bq = (const float*)d_in[5];
    const float* Wk = (const float*)d_in[6];  const float* bk = (const float*)d_in[7];
    const float* Wv = (const float*)d_in[8];  const float* bv = (const float*)d_in[9];
    const float* Wo = (const float*)d_in[10]; const float* bo = (const float*)d_in[11];

    // d_out doubles as scratch; consumed before outproj overwrites d_out.
    char* dc = (char*)d_out;
    bf16*  WqT = (bf16*)dc;                    // [2048][256] bf16, 1 MB
    bf16*  WkT = (bf16*)(dc + 1048576);
    bf16*  WvT = (bf16*)(dc + 2097152);
    float* bqp = (float*)(dc + 3145728);
    float* bkp = (float*)(dc + 3153920);
    float* bvp = (float*)(dc + 3162112);
    float* w   = (float*)(dc + 3170304);       // [16384][64] fp32, 4 MB

    bf16* A = (bf16*)d_ws;                     // scrambled x_att, 64 MB
    const bool big = ws_size >= (67108864ull + 1048576ull);
    bf16* WoT = big ? (bf16*)((char*)d_ws + 67108864) : nullptr;

    prep_kernel<<<big ? 515 : 387, 256, 0, stream>>>(
        Wq, Wk, Wv, bq, bk, bv, Wo, WqT, WkT, WvT, bqp, bkp, bvp, WoT);
    qk_kernel<<<256, 512, 0, stream>>>(
        query, key, mask, WqT, WkT, bqp, bkp, w);
    v_attn_kernel<<<256, 512, 0, stream>>>(value, WvT, bvp, w, A);
    outproj_kernel<<<512, 256, 0, stream>>>(A, WoT, Wo, bo, (float*)d_out);
}